// Round 6
// baseline (411.914 us; speedup 1.0000x reference)
//
#include <hip/hip_runtime.h>
#include <hip/hip_fp16.h>

// GCN 2-layer forward on MI355X — counting-sort CSR build with per-row
// source-sorted adjacency (L2 sweep locality), fp16 line-aligned gather
// arrays, fused agg1+ReLU+GEMM2, fp32 accumulation everywhere.
// d_in: [0]=x (N*128 f32), [1]=edge_index (2*E i32), [2]=W1 (128*64),
//       [3]=b1 (64), [4]=W2 (64*40), [5]=b2 (40)
// d_out: N*40 f32

#define FIN 128
#define H1  64
#define C2  40
#define GP  64            // padded row stride (halves) for g => 128 B lines
#define TILE 8192         // edges per sort tile
#define BCAP 6144         // max edges per 256-dest bucket (mean 4096, sd 64)

// ---------- pass A: per-tile histogram over buckets (bucket = dest >> 8) ----------
__global__ __launch_bounds__(256) void k_hist(const int* __restrict__ col, int E,
                                              int* __restrict__ hist, int NB, int T) {
    extern __shared__ int lh[];          // NB ints
    int t = threadIdx.x, tile = blockIdx.x;
    for (int i = t; i < NB; i += 256) lh[i] = 0;
    __syncthreads();
    int base = tile * TILE;
    int cnt = min(TILE, E - base);
    for (int i = t; i < cnt; i += 256) {
        int c = col[base + i];
        atomicAdd(&lh[c >> 8], 1);
    }
    __syncthreads();
    for (int b = t; b < NB; b += 256) hist[b * T + tile] = lh[b];
}

// ---------- exclusive scan (3 kernels, 512-wide) ----------
__global__ __launch_bounds__(512) void k_scanA(const int* __restrict__ in,
                                               int* __restrict__ out,
                                               int* __restrict__ bsum, int M) {
    __shared__ int s[512];
    int i = blockIdx.x * 512 + threadIdx.x;
    int v = (i < M) ? in[i] : 0;
    s[threadIdx.x] = v;
    __syncthreads();
    for (int off = 1; off < 512; off <<= 1) {
        int u = (threadIdx.x >= off) ? s[threadIdx.x - off] : 0;
        __syncthreads();
        s[threadIdx.x] += u;
        __syncthreads();
    }
    if (i < M) out[i] = s[threadIdx.x] - v;  // exclusive
    if (threadIdx.x == 511) bsum[blockIdx.x] = s[511];
}

__global__ __launch_bounds__(512) void k_scanB(int* __restrict__ bsum, int nb) {
    __shared__ int s[512];
    int t = threadIdx.x;
    int v = (t < nb) ? bsum[t] : 0;
    s[t] = v;
    __syncthreads();
    for (int off = 1; off < 512; off <<= 1) {
        int u = (t >= off) ? s[t - off] : 0;
        __syncthreads();
        s[t] += u;
        __syncthreads();
    }
    if (t < nb) bsum[t] = s[t] - v;
}

__global__ void k_scanC(int* __restrict__ a, const int* __restrict__ bsum, int M) {
    int i = blockIdx.x * blockDim.x + threadIdx.x;
    if (i < M) a[i] += bsum[i >> 9];
}

// ---------- pass B: rank in LDS, stage, write packed pairs per bucket-segment ----------
// packed pair: bits 0..23 = src row, bits 24..31 = dest low 8 bits
__global__ __launch_bounds__(512) void k_scatter(const int* __restrict__ row,
                                                 const int* __restrict__ col,
                                                 const int* __restrict__ scanned,
                                                 int* __restrict__ pairs,
                                                 int E, int NB, int T) {
    __shared__ int2 stage[TILE];         // 64 KB
    __shared__ int lhist[512];
    __shared__ int loff[512];
    __shared__ int gbase[512];
    int t = threadIdx.x, tile = blockIdx.x;
    int base = tile * TILE;
    int cnt = min(TILE, E - base);

    lhist[t] = 0;
    if (t < NB) gbase[t] = scanned[t * T + tile];
    __syncthreads();

    for (int i = t; i < cnt; i += 512) {
        int c = col[base + i];
        atomicAdd(&lhist[c >> 8], 1);
    }
    __syncthreads();

    loff[t] = lhist[t];
    __syncthreads();
    for (int off = 1; off < 512; off <<= 1) {
        int u = (t >= off) ? loff[t - off] : 0;
        __syncthreads();
        loff[t] += u;
        __syncthreads();
    }
    int ex = loff[t] - lhist[t];
    __syncthreads();
    loff[t] = ex;
    lhist[t] = ex;
    __syncthreads();

    for (int i = t; i < cnt; i += 512) {
        int r = row[base + i], c = col[base + i];
        int lpos = atomicAdd(&lhist[c >> 8], 1);
        stage[lpos] = make_int2(r, c);
    }
    __syncthreads();

    for (int i = t; i < cnt; i += 512) {
        int2 p = stage[i];
        int b = p.y >> 8;
        pairs[gbase[b] + (i - loff[b])] = p.x | ((p.y & 255) << 24);
    }
}

// ---------- pass C: per-bucket sort by dest, then per-row sort sources asc. ----------
__global__ __launch_bounds__(256) void k_bucket(const int* __restrict__ pairs,
                                                const int* __restrict__ scanned,
                                                int* __restrict__ rowptr,
                                                int* __restrict__ deg,
                                                float* __restrict__ dinv,
                                                int* __restrict__ esrc,
                                                int N, int E, int NB, int T) {
    __shared__ int dcnt[256];
    __shared__ int cur[256];
    __shared__ int outbuf[BCAP];         // 24 KB
    int t = threadIdx.x, b = blockIdx.x;
    int d0 = b << 8;
    int nd = min(256, N - d0);
    int bstart = scanned[b * T];
    int bend = (b + 1 < NB) ? scanned[(b + 1) * T] : E;
    int cnt = bend - bstart;

    dcnt[t] = 0;
    __syncthreads();
    for (int i = t; i < cnt; i += 256) {
        unsigned p = (unsigned)pairs[bstart + i];
        atomicAdd(&dcnt[p >> 24], 1);
    }
    __syncthreads();

    // inclusive scan -> exclusive
    int myc = dcnt[t];
    cur[t] = myc;
    __syncthreads();
    for (int off = 1; off < 256; off <<= 1) {
        int u = (t >= off) ? cur[t - off] : 0;
        __syncthreads();
        cur[t] += u;
        __syncthreads();
    }
    int ex = cur[t] - myc;
    __syncthreads();
    cur[t] = ex;
    if (t < nd) {
        int node = d0 + t;
        rowptr[node] = bstart + ex;
        deg[node] = myc;
        dinv[node] = rsqrtf((float)myc + 1.0f);
    }
    __syncthreads();

    if (cnt <= BCAP) {
        for (int i = t; i < cnt; i += 256) {
            unsigned p = (unsigned)pairs[bstart + i];
            int lpos = atomicAdd(&cur[p >> 24], 1);
            outbuf[lpos] = (int)(p & 0xFFFFFF);
        }
        __syncthreads();
        // per-row insertion sort of sources (ascending): approximately
        // synchronized L2 sweep across concurrently-running agg waves
        for (int j = 1; j < myc; ++j) {
            int v = outbuf[ex + j];
            int k2 = j - 1;
            while (k2 >= 0 && outbuf[ex + k2] > v) {
                outbuf[ex + k2 + 1] = outbuf[ex + k2];
                --k2;
            }
            outbuf[ex + k2 + 1] = v;
        }
        __syncthreads();
        for (int i = t; i < cnt; i += 256) esrc[bstart + i] = outbuf[i];
    } else {
        // safety fallback (never taken for this input distribution)
        for (int i = t; i < cnt; i += 256) {
            unsigned p = (unsigned)pairs[bstart + i];
            int lpos = atomicAdd(&cur[p >> 24], 1);
            esrc[bstart + lpos] = (int)(p & 0xFFFFFF);
        }
    }
}

// ---------- GEMM1: h1 = fp16(x @ W1)  (N x 128)@(128 x 64), 64x64 tile ----------
__global__ __launch_bounds__(256) void k_gemm1(const float* __restrict__ x,
                                               const float* __restrict__ W1,
                                               __half* __restrict__ h1, int N) {
    __shared__ float Ws[FIN * H1];        // 32 KB, [k][o]
    __shared__ float xs[64][FIN + 4];
    int t = threadIdx.x;
    int node0 = blockIdx.x * 64;

    const float4* W4 = (const float4*)W1;
    float4* Ws4 = (float4*)Ws;
#pragma unroll
    for (int j = 0; j < 8; ++j) Ws4[t + j * 256] = W4[t + j * 256];

    const float4* x4 = (const float4*)x;
#pragma unroll
    for (int j = 0; j < 8; ++j) {
        int idx = t + j * 256;
        int r = idx >> 5, kq = idx & 31;
        int node = node0 + r; if (node >= N) node = N - 1;
        float4 v = x4[(size_t)node * 32 + kq];
        *(float4*)&xs[r][kq * 4] = v;
    }
    __syncthreads();

    int og = t & 15, ng = t >> 4;
    int o0 = og * 4, n0 = ng * 4;
    float acc[4][4];
#pragma unroll
    for (int i = 0; i < 4; ++i)
#pragma unroll
        for (int j = 0; j < 4; ++j) acc[i][j] = 0.f;

#pragma unroll 8
    for (int k = 0; k < FIN; ++k) {
        float a0 = xs[n0 + 0][k], a1 = xs[n0 + 1][k];
        float a2 = xs[n0 + 2][k], a3 = xs[n0 + 3][k];
        float4 w = *(const float4*)&Ws[k * H1 + o0];
        acc[0][0] += a0 * w.x; acc[0][1] += a0 * w.y; acc[0][2] += a0 * w.z; acc[0][3] += a0 * w.w;
        acc[1][0] += a1 * w.x; acc[1][1] += a1 * w.y; acc[1][2] += a1 * w.z; acc[1][3] += a1 * w.w;
        acc[2][0] += a2 * w.x; acc[2][1] += a2 * w.y; acc[2][2] += a2 * w.z; acc[2][3] += a2 * w.w;
        acc[3][0] += a3 * w.x; acc[3][1] += a3 * w.y; acc[3][2] += a3 * w.z; acc[3][3] += a3 * w.w;
    }

#pragma unroll
    for (int i = 0; i < 4; ++i) {
        int node = node0 + n0 + i;
        if (node < N) {
            union { __half h[4]; uint2 u; } pk;
            pk.h[0] = __float2half_rn(acc[i][0]);
            pk.h[1] = __float2half_rn(acc[i][1]);
            pk.h[2] = __float2half_rn(acc[i][2]);
            pk.h[3] = __float2half_rn(acc[i][3]);
            *(uint2*)&h1[(size_t)node * H1 + o0] = pk.u;
        }
    }
}

// ---------- fused: agg1 + b1 + ReLU + GEMM2 -> g (fp16, stride GP) ----------
// wave per node (4 waves/block). Lane = feature for agg; lanes 0..39 hold the
// 40 outputs of the W2 dot (via __shfl broadcast of the agg row).
__global__ __launch_bounds__(256) void k_aggmm(const int* __restrict__ rowptr,
                                               const int* __restrict__ deg,
                                               const int* __restrict__ esrc,
                                               const __half* __restrict__ h1,
                                               const float* __restrict__ dinv,
                                               const float* __restrict__ b1,
                                               const float* __restrict__ W2,
                                               __half* __restrict__ g, int N) {
    __shared__ float W2s[H1 * C2];       // 10 KB, [k][c]
    int t = threadIdx.x;
    {   // stage W2
        const float4* W4 = (const float4*)W2;
        float4* Ws4 = (float4*)W2s;
        for (int i = t; i < (H1 * C2) / 4; i += 256) Ws4[i] = W4[i];
    }
    __syncthreads();

    int w = (blockIdx.x * blockDim.x + t) >> 6;
    int lane = t & 63;
    if (w >= N) return;

    int start = rowptr[w], d = deg[w];
    float dc = dinv[w];
    float acc = dc * dc * __half2float(h1[(size_t)w * H1 + lane]) + b1[lane];
    int i = 0;
    for (; i + 4 <= d; i += 4) {
        int e = start + i;
        int r0 = esrc[e], r1 = esrc[e + 1], r2 = esrc[e + 2], r3 = esrc[e + 3];
        float w0 = dinv[r0] * dc, w1 = dinv[r1] * dc;
        float w2 = dinv[r2] * dc, w3 = dinv[r3] * dc;
        float v0 = __half2float(h1[(size_t)r0 * H1 + lane]);
        float v1 = __half2float(h1[(size_t)r1 * H1 + lane]);
        float v2 = __half2float(h1[(size_t)r2 * H1 + lane]);
        float v3 = __half2float(h1[(size_t)r3 * H1 + lane]);
        acc += w0 * v0 + w1 * v1 + w2 * v2 + w3 * v3;
    }
    for (; i < d; ++i) {
        int r = esrc[start + i];
        acc += dinv[r] * dc * __half2float(h1[(size_t)r * H1 + lane]);
    }

    // ReLU then x W2 within the wave: lane c accumulates column c
    float rv = fmaxf(acc, 0.f);
    int cc = (lane < C2) ? lane : (C2 - 1);
    float o = 0.f;
#pragma unroll
    for (int k = 0; k < H1; ++k)
        o += __shfl(rv, k) * W2s[k * C2 + cc];

    if (lane < C2) g[(size_t)w * GP + lane] = __float2half_rn(o);
}

// ---------- agg2: one wave per node, lanes 0..39; fp16 line-aligned gather ----------
__global__ __launch_bounds__(256) void k_agg2(const int* __restrict__ rowptr,
                                              const int* __restrict__ deg,
                                              const int* __restrict__ esrc,
                                              const __half* __restrict__ g,
                                              const float* __restrict__ dinv,
                                              const float* __restrict__ b2,
                                              float* __restrict__ out, int N) {
    int w = (blockIdx.x * blockDim.x + threadIdx.x) >> 6;
    int lane = threadIdx.x & 63;
    if (w >= N || lane >= C2) return;
    int start = rowptr[w], d = deg[w];
    float dc = dinv[w];
    float acc = dc * dc * __half2float(g[(size_t)w * GP + lane]);
    int i = 0;
    for (; i + 4 <= d; i += 4) {
        int e = start + i;
        int r0 = esrc[e], r1 = esrc[e + 1], r2 = esrc[e + 2], r3 = esrc[e + 3];
        float w0 = dinv[r0] * dc, w1 = dinv[r1] * dc;
        float w2 = dinv[r2] * dc, w3 = dinv[r3] * dc;
        float v0 = __half2float(g[(size_t)r0 * GP + lane]);
        float v1 = __half2float(g[(size_t)r1 * GP + lane]);
        float v2 = __half2float(g[(size_t)r2 * GP + lane]);
        float v3 = __half2float(g[(size_t)r3 * GP + lane]);
        acc += w0 * v0 + w1 * v1 + w2 * v2 + w3 * v3;
    }
    for (; i < d; ++i) {
        int r = esrc[start + i];
        acc += dinv[r] * dc * __half2float(g[(size_t)r * GP + lane]);
    }
    out[(size_t)w * C2 + lane] = acc + b2[lane];
}

extern "C" void kernel_launch(void* const* d_in, const int* in_sizes, int n_in,
                              void* d_out, int out_size, void* d_ws, size_t ws_size,
                              hipStream_t stream) {
    const float* x   = (const float*)d_in[0];
    const int*   ei  = (const int*)d_in[1];
    const float* W1  = (const float*)d_in[2];
    const float* b1  = (const float*)d_in[3];
    const float* W2  = (const float*)d_in[4];
    const float* b2  = (const float*)d_in[5];
    float* out = (float*)d_out;

    const int N = in_sizes[0] / FIN;       // 100000
    const int E = in_sizes[1] / 2;         // 1600000
    const int* row = ei;
    const int* col = ei + E;

    const int NB = (N + 255) >> 8;         // 391 buckets
    const int T  = (E + TILE - 1) / TILE;  // 196 tiles
    const int M  = NB * T;                 // 76,636 hist entries

    // workspace layout
    char* ws = (char*)d_ws;
    size_t off = 0;
    int*    hist    = (int*)(ws + off);    off += (size_t)M * 4;
    int*    scanned = (int*)(ws + off);    off += (size_t)M * 4;
    int*    bsum    = (int*)(ws + off);    off += 1024 * 4;
    int*    deg     = (int*)(ws + off);    off += (size_t)N * 4;
    int*    rowptr  = (int*)(ws + off);    off += (size_t)N * 4;
    float*  dinv    = (float*)(ws + off);  off += (size_t)N * 4;
    int*    pairs   = (int*)(ws + off);    off += (size_t)E * 4;
    int*    esrc    = (int*)(ws + off);    off += (size_t)E * 4;
    __half* h1      = (__half*)(ws + off); off += (size_t)N * H1 * 2;
    __half* g       = (__half*)(ws + off); off += (size_t)N * GP * 2;

    int gblocks = (N + 63) / 64;
    k_gemm1<<<gblocks, 256, 0, stream>>>(x, W1, h1, N);

    // CSR build (counting sort, packed pairs, per-row source-sorted)
    k_hist<<<T, 256, NB * 4, stream>>>(col, E, hist, NB, T);
    int snb = (M + 511) / 512;             // 150
    k_scanA<<<snb, 512, 0, stream>>>(hist, scanned, bsum, M);
    k_scanB<<<1, 512, 0, stream>>>(bsum, snb);
    k_scanC<<<(M + 255) / 256, 256, 0, stream>>>(scanned, bsum, M);
    k_scatter<<<T, 512, 0, stream>>>(row, col, scanned, pairs, E, NB, T);
    k_bucket<<<NB, 256, 0, stream>>>(pairs, scanned, rowptr, deg, dinv, esrc, N, E, NB, T);

    // layer 1 aggregation fused with ReLU + GEMM2
    k_aggmm<<<((size_t)N * 64 + 255) / 256, 256, 0, stream>>>(rowptr, deg, esrc, h1, dinv, b1, W2, g, N);

    // layer 2 aggregation + bias
    k_agg2<<<((size_t)N * 64 + 255) / 256, 256, 0, stream>>>(rowptr, deg, esrc, g, dinv, b2, out, N);
}

// Round 7
// 295.976 us; speedup vs baseline: 1.3917x; 1.3917x over previous
//
#include <hip/hip_runtime.h>
#include <hip/hip_fp16.h>

// GCN 2-layer forward on MI355X.
// Counting-sort CSR build (chunk-claim, no big scan), rows padded to x4 with
// weight-0 sentinel (node N, dinv[N]=0) => tail-free int4 edge loops.
// fp16 line-aligned gather arrays, fp32 accumulation, register-tiled GEMMs.
// d_in: [0]=x (N*128 f32), [1]=edge_index (2*E i32), [2]=W1 (128*64),
//       [3]=b1 (64), [4]=W2 (64*40), [5]=b2 (40)
// d_out: N*40 f32

#define FIN 128
#define H1  64
#define C2  40
#define GP  64            // padded row stride (halves) for g => 128 B lines
#define TILE 8192         // edges per tile
#define BCAP 6144         // padded bucket capacity (mean 4096+768 pad, sd 64)

// ---------- global bucket histogram (bucket = dest >> 8) ----------
__global__ __launch_bounds__(256) void k_hist(const int* __restrict__ col, int E,
                                              int* __restrict__ bucketCnt, int NB) {
    extern __shared__ int lh[];
    int t = threadIdx.x;
    for (int i = t; i < NB; i += 256) lh[i] = 0;
    __syncthreads();
    int base = blockIdx.x * TILE;
    int cnt = min(TILE, E - base);
    for (int i = t; i < cnt; i += 256) atomicAdd(&lh[col[base + i] >> 8], 1);
    __syncthreads();
    for (int b = t; b < NB; b += 256) if (lh[b]) atomicAdd(&bucketCnt[b], lh[b]);
}

// ---------- single-block scan over NB buckets: raw & padded bases ----------
__global__ __launch_bounds__(512) void k_scan(const int* __restrict__ bucketCnt,
                                              int* __restrict__ rawBase,
                                              int* __restrict__ padBase,
                                              int* __restrict__ gcursor,
                                              float* __restrict__ dinv,
                                              int NB, int N) {
    __shared__ int sr[512], sp[512];
    int t = threadIdx.x;
    int c = (t < NB) ? bucketCnt[t] : 0;
    int p = (t < NB) ? (((c + 3) & ~3) + 1024) : 0;   // room for per-dest x4 pad
    sr[t] = c; sp[t] = p;
    __syncthreads();
    for (int off = 1; off < 512; off <<= 1) {
        int a = (t >= off) ? sr[t - off] : 0;
        int b = (t >= off) ? sp[t - off] : 0;
        __syncthreads();
        sr[t] += a; sp[t] += b;
        __syncthreads();
    }
    if (t <= NB) {
        int rex = sr[t] - ((t < NB) ? c : 0);   // exclusive (t==NB -> total)
        int pex = sp[t] - ((t < NB) ? p : 0);
        rawBase[t] = rex;
        padBase[t] = pex;
        if (t < NB) gcursor[t] = rex;
    }
    if (t == 0) dinv[N] = 0.f;                  // sentinel: weight 0
}

// ---------- scatter into bucket-contiguous chunks (packed pairs) ----------
// packed: bits 0..23 = src row, bits 24..31 = dest low 8
__global__ __launch_bounds__(512) void k_scatter(const int* __restrict__ row,
                                                 const int* __restrict__ col,
                                                 int* __restrict__ gcursor,
                                                 int* __restrict__ pairs,
                                                 int E, int NB) {
    __shared__ int2 stage[TILE];         // 64 KB
    __shared__ int lcnt[512];            // per-bucket count, then cursor
    __shared__ int lex[512];             // exclusive local offsets
    __shared__ int gbase[512];           // claimed global chunk base
    int t = threadIdx.x, tile = blockIdx.x;
    int base = tile * TILE;
    int cnt = min(TILE, E - base);

    lcnt[t] = 0;
    __syncthreads();
    for (int i = t; i < cnt; i += 512) atomicAdd(&lcnt[col[base + i] >> 8], 1);
    __syncthreads();

    int myc = lcnt[t];
    lex[t] = myc;
    __syncthreads();
    for (int off = 1; off < 512; off <<= 1) {
        int u = (t >= off) ? lex[t - off] : 0;
        __syncthreads();
        lex[t] += u;
        __syncthreads();
    }
    int ex = lex[t] - myc;
    __syncthreads();
    lex[t] = ex;
    lcnt[t] = ex;                         // local cursor
    if (t < NB && myc > 0) gbase[t] = atomicAdd(&gcursor[t], myc);
    __syncthreads();

    for (int i = t; i < cnt; i += 512) {
        int r = row[base + i], c = col[base + i];
        int lpos = atomicAdd(&lcnt[c >> 8], 1);
        stage[lpos] = make_int2(r, c);
    }
    __syncthreads();

    for (int i = t; i < cnt; i += 512) {
        int2 p = stage[i];
        int b = p.y >> 8;
        pairs[gbase[b] + (i - lex[b])] = p.x | ((p.y & 255) << 24);
    }
}

// ---------- per-bucket final sort by dest; padded esrc segments ----------
__global__ __launch_bounds__(256) void k_bucket(const int* __restrict__ pairs,
                                                const int* __restrict__ rawBase,
                                                const int* __restrict__ padBase,
                                                int* __restrict__ rowptr,
                                                int* __restrict__ deg,
                                                float* __restrict__ dinv,
                                                int* __restrict__ esrc,
                                                int N, int NB) {
    __shared__ int dcnt[256];
    __shared__ int sr[256], sp[256];
    __shared__ int cur[256];
    __shared__ int outbuf[BCAP];         // 24 KB
    int t = threadIdx.x, b = blockIdx.x;
    int d0 = b << 8;
    int nd = min(256, N - d0);
    int bstart = rawBase[b];
    int cnt = rawBase[b + 1] - bstart;
    int pstart = padBase[b];

    dcnt[t] = 0;
    __syncthreads();
    for (int i = t; i < cnt; i += 256) {
        unsigned p = (unsigned)pairs[bstart + i];
        atomicAdd(&dcnt[p >> 24], 1);
    }
    __syncthreads();

    int myc = dcnt[t];
    int myp = (myc + 3) & ~3;            // padded per-dest count
    sr[t] = myc; sp[t] = myp;
    __syncthreads();
    for (int off = 1; off < 256; off <<= 1) {
        int a = (t >= off) ? sr[t - off] : 0;
        int c2 = (t >= off) ? sp[t - off] : 0;
        __syncthreads();
        sr[t] += a; sp[t] += c2;
        __syncthreads();
    }
    int pex = sp[t] - myp;               // exclusive padded offset
    int pcnt = sp[255];                  // total padded content
    __syncthreads();
    cur[t] = pex;                        // placement cursor (padded layout)
    if (t < nd) {
        int node = d0 + t;
        rowptr[node] = pstart + pex;
        deg[node] = myc;
        dinv[node] = rsqrtf((float)myc + 1.0f);
    }
    __syncthreads();

    if (pcnt <= BCAP) {
        for (int i = t; i < cnt; i += 256) {
            unsigned p = (unsigned)pairs[bstart + i];
            int lpos = atomicAdd(&cur[p >> 24], 1);
            outbuf[lpos] = (int)(p & 0xFFFFFF);
        }
        __syncthreads();
        // fill per-dest pad slots with sentinel N (weight 0)
        for (int j = myc; j < myp; ++j) outbuf[pex + j] = N;
        __syncthreads();
        for (int i = t; i < pcnt; i += 256) esrc[pstart + i] = outbuf[i];
    } else {
        // safety fallback (never taken for this distribution)
        for (int i = t; i < cnt; i += 256) {
            unsigned p = (unsigned)pairs[bstart + i];
            int lpos = atomicAdd(&cur[p >> 24], 1);
            esrc[pstart + lpos] = (int)(p & 0xFFFFFF);
        }
        __syncthreads();
        for (int j = myc; j < myp; ++j) esrc[pstart + pex + j] = N;
    }
}

// ---------- GEMM1: h1 = fp16(x @ W1)  (N x 128)@(128 x 64), 64x64 tile ----------
__global__ __launch_bounds__(256) void k_gemm1(const float* __restrict__ x,
                                               const float* __restrict__ W1,
                                               __half* __restrict__ h1, int N) {
    __shared__ float Ws[FIN * H1];        // 32 KB, [k][o]
    __shared__ float xs[64][FIN + 4];
    int t = threadIdx.x;
    int node0 = blockIdx.x * 64;

    const float4* W4 = (const float4*)W1;
    float4* Ws4 = (float4*)Ws;
#pragma unroll
    for (int j = 0; j < 8; ++j) Ws4[t + j * 256] = W4[t + j * 256];

    const float4* x4 = (const float4*)x;
#pragma unroll
    for (int j = 0; j < 8; ++j) {
        int idx = t + j * 256;
        int r = idx >> 5, kq = idx & 31;
        int node = node0 + r; if (node >= N) node = N - 1;
        float4 v = x4[(size_t)node * 32 + kq];
        *(float4*)&xs[r][kq * 4] = v;
    }
    __syncthreads();

    int og = t & 15, ng = t >> 4;
    int o0 = og * 4, n0 = ng * 4;
    float acc[4][4];
#pragma unroll
    for (int i = 0; i < 4; ++i)
#pragma unroll
        for (int j = 0; j < 4; ++j) acc[i][j] = 0.f;

#pragma unroll 8
    for (int k = 0; k < FIN; ++k) {
        float a0 = xs[n0 + 0][k], a1 = xs[n0 + 1][k];
        float a2 = xs[n0 + 2][k], a3 = xs[n0 + 3][k];
        float4 w = *(const float4*)&Ws[k * H1 + o0];
        acc[0][0] += a0 * w.x; acc[0][1] += a0 * w.y; acc[0][2] += a0 * w.z; acc[0][3] += a0 * w.w;
        acc[1][0] += a1 * w.x; acc[1][1] += a1 * w.y; acc[1][2] += a1 * w.z; acc[1][3] += a1 * w.w;
        acc[2][0] += a2 * w.x; acc[2][1] += a2 * w.y; acc[2][2] += a2 * w.z; acc[2][3] += a2 * w.w;
        acc[3][0] += a3 * w.x; acc[3][1] += a3 * w.y; acc[3][2] += a3 * w.z; acc[3][3] += a3 * w.w;
    }

#pragma unroll
    for (int i = 0; i < 4; ++i) {
        int node = node0 + n0 + i;
        if (node < N) {
            union { __half h[4]; uint2 u; } pk;
            pk.h[0] = __float2half_rn(acc[i][0]);
            pk.h[1] = __float2half_rn(acc[i][1]);
            pk.h[2] = __float2half_rn(acc[i][2]);
            pk.h[3] = __float2half_rn(acc[i][3]);
            *(uint2*)&h1[(size_t)node * H1 + o0] = pk.u;
        }
    }
}

// ---------- agg1: wave per node, lane = feature; int4 edge loop, no tail ----------
__global__ __launch_bounds__(256) void k_agg1(const int* __restrict__ rowptr,
                                              const int* __restrict__ deg,
                                              const int* __restrict__ esrc,
                                              const __half* __restrict__ h1,
                                              const float* __restrict__ dinv,
                                              const float* __restrict__ b1,
                                              float* __restrict__ agg, int N) {
    int w = (blockIdx.x * blockDim.x + threadIdx.x) >> 6;
    int lane = threadIdx.x & 63;
    if (w >= N) return;
    int start = rowptr[w], d = deg[w];
    int d4 = (d + 3) & ~3;
    float dc = dinv[w];
    float acc = dc * dc * __half2float(h1[(size_t)w * H1 + lane]);
    int i = 0;
    for (; i + 8 <= d4; i += 8) {
        int4 ra = *(const int4*)&esrc[start + i];
        int4 rb = *(const int4*)&esrc[start + i + 4];
        float w0 = dinv[ra.x] * dc, w1 = dinv[ra.y] * dc;
        float w2 = dinv[ra.z] * dc, w3 = dinv[ra.w] * dc;
        float w4 = dinv[rb.x] * dc, w5 = dinv[rb.y] * dc;
        float w6 = dinv[rb.z] * dc, w7 = dinv[rb.w] * dc;
        float v0 = __half2float(h1[(size_t)ra.x * H1 + lane]);
        float v1 = __half2float(h1[(size_t)ra.y * H1 + lane]);
        float v2 = __half2float(h1[(size_t)ra.z * H1 + lane]);
        float v3 = __half2float(h1[(size_t)ra.w * H1 + lane]);
        float v4 = __half2float(h1[(size_t)rb.x * H1 + lane]);
        float v5 = __half2float(h1[(size_t)rb.y * H1 + lane]);
        float v6 = __half2float(h1[(size_t)rb.z * H1 + lane]);
        float v7 = __half2float(h1[(size_t)rb.w * H1 + lane]);
        acc += w0 * v0 + w1 * v1 + w2 * v2 + w3 * v3;
        acc += w4 * v4 + w5 * v5 + w6 * v6 + w7 * v7;
    }
    if (i < d4) {
        int4 ra = *(const int4*)&esrc[start + i];
        float w0 = dinv[ra.x] * dc, w1 = dinv[ra.y] * dc;
        float w2 = dinv[ra.z] * dc, w3 = dinv[ra.w] * dc;
        float v0 = __half2float(h1[(size_t)ra.x * H1 + lane]);
        float v1 = __half2float(h1[(size_t)ra.y * H1 + lane]);
        float v2 = __half2float(h1[(size_t)ra.z * H1 + lane]);
        float v3 = __half2float(h1[(size_t)ra.w * H1 + lane]);
        acc += w0 * v0 + w1 * v1 + w2 * v2 + w3 * v3;
    }
    agg[(size_t)w * H1 + lane] = acc + b1[lane];
}

// ---------- GEMM2: g = fp16(relu(agg1) @ W2), padded row stride GP ----------
__global__ __launch_bounds__(256) void k_gemm2(const float* __restrict__ agg1,
                                               const float* __restrict__ W2,
                                               __half* __restrict__ g, int N) {
    __shared__ float Ws[H1 * C2];
    __shared__ float hs[64][H1 + 4];
    int t = threadIdx.x;
    int node0 = blockIdx.x * 64;

    const float4* W4 = (const float4*)W2;
    float4* Ws4 = (float4*)Ws;
    for (int i = t; i < 640; i += 256) Ws4[i] = W4[i];

    const float4* a4 = (const float4*)agg1;
#pragma unroll
    for (int j = 0; j < 4; ++j) {
        int idx = t + j * 256;
        int r = idx >> 4, kq = idx & 15;
        int node = node0 + r; if (node >= N) node = N - 1;
        float4 v = a4[(size_t)node * 16 + kq];
        v.x = fmaxf(v.x, 0.f); v.y = fmaxf(v.y, 0.f);
        v.z = fmaxf(v.z, 0.f); v.w = fmaxf(v.w, 0.f);
        *(float4*)&hs[r][kq * 4] = v;
    }
    __syncthreads();

    int og = t & 15, ng = t >> 4;
    int o0 = og * 4, n0 = ng * 4;
    int o0c = (o0 <= 36) ? o0 : 36;
    float acc[4][4];
#pragma unroll
    for (int i = 0; i < 4; ++i)
#pragma unroll
        for (int j = 0; j < 4; ++j) acc[i][j] = 0.f;

#pragma unroll 8
    for (int k = 0; k < H1; ++k) {
        float a0 = hs[n0 + 0][k], a1 = hs[n0 + 1][k];
        float a2 = hs[n0 + 2][k], a3 = hs[n0 + 3][k];
        float4 w = *(const float4*)&Ws[k * C2 + o0c];
        acc[0][0] += a0 * w.x; acc[0][1] += a0 * w.y; acc[0][2] += a0 * w.z; acc[0][3] += a0 * w.w;
        acc[1][0] += a1 * w.x; acc[1][1] += a1 * w.y; acc[1][2] += a1 * w.z; acc[1][3] += a1 * w.w;
        acc[2][0] += a2 * w.x; acc[2][1] += a2 * w.y; acc[2][2] += a2 * w.z; acc[2][3] += a2 * w.w;
        acc[3][0] += a3 * w.x; acc[3][1] += a3 * w.y; acc[3][2] += a3 * w.z; acc[3][3] += a3 * w.w;
    }

    if (o0 < C2) {
#pragma unroll
        for (int i = 0; i < 4; ++i) {
            int node = node0 + n0 + i;
            if (node < N) {
                union { __half h[4]; uint2 u; } pk;
                pk.h[0] = __float2half_rn(acc[i][0]);
                pk.h[1] = __float2half_rn(acc[i][1]);
                pk.h[2] = __float2half_rn(acc[i][2]);
                pk.h[3] = __float2half_rn(acc[i][3]);
                *(uint2*)&g[(size_t)node * GP + o0] = pk.u;
            }
        }
    }
}

// ---------- agg2: wave per node, lanes 0..39; int4 edge loop ----------
__global__ __launch_bounds__(256) void k_agg2(const int* __restrict__ rowptr,
                                              const int* __restrict__ deg,
                                              const int* __restrict__ esrc,
                                              const __half* __restrict__ g,
                                              const float* __restrict__ dinv,
                                              const float* __restrict__ b2,
                                              float* __restrict__ out, int N) {
    int w = (blockIdx.x * blockDim.x + threadIdx.x) >> 6;
    int lane = threadIdx.x & 63;
    if (w >= N || lane >= C2) return;
    int start = rowptr[w], d = deg[w];
    int d4 = (d + 3) & ~3;
    float dc = dinv[w];
    float acc = dc * dc * __half2float(g[(size_t)w * GP + lane]);
    int i = 0;
    for (; i + 8 <= d4; i += 8) {
        int4 ra = *(const int4*)&esrc[start + i];
        int4 rb = *(const int4*)&esrc[start + i + 4];
        float w0 = dinv[ra.x] * dc, w1 = dinv[ra.y] * dc;
        float w2 = dinv[ra.z] * dc, w3 = dinv[ra.w] * dc;
        float w4 = dinv[rb.x] * dc, w5 = dinv[rb.y] * dc;
        float w6 = dinv[rb.z] * dc, w7 = dinv[rb.w] * dc;
        float v0 = __half2float(g[(size_t)ra.x * GP + lane]);
        float v1 = __half2float(g[(size_t)ra.y * GP + lane]);
        float v2 = __half2float(g[(size_t)ra.z * GP + lane]);
        float v3 = __half2float(g[(size_t)ra.w * GP + lane]);
        float v4 = __half2float(g[(size_t)rb.x * GP + lane]);
        float v5 = __half2float(g[(size_t)rb.y * GP + lane]);
        float v6 = __half2float(g[(size_t)rb.z * GP + lane]);
        float v7 = __half2float(g[(size_t)rb.w * GP + lane]);
        acc += w0 * v0 + w1 * v1 + w2 * v2 + w3 * v3;
        acc += w4 * v4 + w5 * v5 + w6 * v6 + w7 * v7;
    }
    if (i < d4) {
        int4 ra = *(const int4*)&esrc[start + i];
        float w0 = dinv[ra.x] * dc, w1 = dinv[ra.y] * dc;
        float w2 = dinv[ra.z] * dc, w3 = dinv[ra.w] * dc;
        float v0 = __half2float(g[(size_t)ra.x * GP + lane]);
        float v1 = __half2float(g[(size_t)ra.y * GP + lane]);
        float v2 = __half2float(g[(size_t)ra.z * GP + lane]);
        float v3 = __half2float(g[(size_t)ra.w * GP + lane]);
        acc += w0 * v0 + w1 * v1 + w2 * v2 + w3 * v3;
    }
    out[(size_t)w * C2 + lane] = acc + b2[lane];
}

extern "C" void kernel_launch(void* const* d_in, const int* in_sizes, int n_in,
                              void* d_out, int out_size, void* d_ws, size_t ws_size,
                              hipStream_t stream) {
    const float* x   = (const float*)d_in[0];
    const int*   ei  = (const int*)d_in[1];
    const float* W1  = (const float*)d_in[2];
    const float* b1  = (const float*)d_in[3];
    const float* W2  = (const float*)d_in[4];
    const float* b2  = (const float*)d_in[5];
    float* out = (float*)d_out;

    const int N = in_sizes[0] / FIN;       // 100000
    const int E = in_sizes[1] / 2;         // 1600000
    const int* row = ei;
    const int* col = ei + E;

    const int NB = (N + 255) >> 8;         // 391 buckets
    const int T  = (E + TILE - 1) / TILE;  // 196 tiles
    const int EP = E + NB * 1024 + 1024;   // padded esrc capacity

    // workspace layout
    char* ws = (char*)d_ws;
    size_t off = 0;
    int*    bucketCnt = (int*)(ws + off);    off += (size_t)NB * 4;
    int*    rawBase   = (int*)(ws + off);    off += (size_t)(NB + 1) * 4;
    int*    padBase   = (int*)(ws + off);    off += (size_t)(NB + 1) * 4;
    int*    gcursor   = (int*)(ws + off);    off += (size_t)NB * 4;
    int*    deg       = (int*)(ws + off);    off += (size_t)N * 4;
    int*    rowptr    = (int*)(ws + off);    off += (size_t)N * 4;
    float*  dinv      = (float*)(ws + off);  off += (size_t)(N + 1) * 4;
    int*    pairs     = (int*)(ws + off);    off += (size_t)E * 4;
    int*    esrc      = (int*)(ws + off);    off += (size_t)EP * 4;
    __half* h1        = (__half*)(ws + off); off += (size_t)(N + 1) * H1 * 2;
    float*  agg1      = (float*)(ws + off);  off += (size_t)N * H1 * 4;
    __half* g         = (__half*)(ws + off); off += (size_t)(N + 1) * GP * 2;

    hipMemsetAsync(bucketCnt, 0, (size_t)NB * 4, stream);

    int gblocks = (N + 63) / 64;
    k_gemm1<<<gblocks, 256, 0, stream>>>(x, W1, h1, N);

    // CSR build: hist -> scan (1 block) -> chunk-claim scatter -> bucket sort
    k_hist<<<T, 256, NB * 4, stream>>>(col, E, bucketCnt, NB);
    k_scan<<<1, 512, 0, stream>>>(bucketCnt, rawBase, padBase, gcursor, dinv, NB, N);
    k_scatter<<<T, 512, 0, stream>>>(row, col, gcursor, pairs, E, NB);
    k_bucket<<<NB, 256, 0, stream>>>(pairs, rawBase, padBase, rowptr, deg, dinv, esrc, N, NB);

    // layer 1
    k_agg1<<<((size_t)N * 64 + 255) / 256, 256, 0, stream>>>(rowptr, deg, esrc, h1, dinv, b1, agg1, N);

    // layer 2
    k_gemm2<<<gblocks, 256, 0, stream>>>(agg1, W2, g, N);
    k_agg2<<<((size_t)N * 64 + 255) / 256, 256, 0, stream>>>(rowptr, deg, esrc, g, dinv, b2, out, N);
}